// Round 7
// baseline (253.988 us; speedup 1.0000x reference)
//
#include <hip/hip_runtime.h>
#include <hip/hip_bf16.h>
#include <math.h>

#define DIMX   1024
#define HEADS  16
#define DH     64
#define NB     8
#define NSEQ   1024
#define ROWS   (NB * NSEQ)        // 8192
#define QKVW   (3 * DIMX)         // 3072
#define LOG2E  1.44269504088896f

typedef _Float16 half8 __attribute__((ext_vector_type(8)));
typedef _Float16 half4 __attribute__((ext_vector_type(4)));
typedef float floatx4 __attribute__((ext_vector_type(4)));

// async global->LDS, 16B per lane. lptr must be wave-uniform; HW adds lane*16.
#define GLD_LDS16(gptr, lptr) __builtin_amdgcn_global_load_lds( \
    (const __attribute__((address_space(1))) void*)(gptr),      \
    (__attribute__((address_space(3))) void*)(lptr), 16, 0, 0)

__device__ __forceinline__ float fexp2(float x) {
#if __has_builtin(__builtin_amdgcn_exp2f)
    return __builtin_amdgcn_exp2f(x);
#else
    return __expf(x * 0.69314718056f);
#endif
}

// ---------------------------------------------------------------------------
// Kernel 1: merged LayerNorm (one wave per row; blocks 0..2047) + weight
// transpose (blocks 2048..6143).
// ---------------------------------------------------------------------------
__global__ __launch_bounds__(256) void lnw_kernel(const float* __restrict__ x,
                                                  const float* __restrict__ gamma,
                                                  const float* __restrict__ Wq,
                                                  const float* __restrict__ Wo,
                                                  _Float16* __restrict__ xn,
                                                  _Float16* __restrict__ WqT,
                                                  _Float16* __restrict__ WoT) {
    __shared__ float tile[32][33];
    int t = threadIdx.x;

    if (blockIdx.x < ROWS / 4) {
        int wave = t >> 6, lane = t & 63;
        int row = blockIdx.x * 4 + wave;
        const float* xr = x + (size_t)row * DIMX;
        _Float16* xo = xn + (size_t)row * DIMX;

        float4 v[4];
        float s = 0.f, ss = 0.f;
        #pragma unroll
        for (int i = 0; i < 4; i++) {
            v[i] = ((const float4*)xr)[lane + 64 * i];
            s  += v[i].x + v[i].y + v[i].z + v[i].w;
            ss += v[i].x*v[i].x + v[i].y*v[i].y + v[i].z*v[i].z + v[i].w*v[i].w;
        }
        #pragma unroll
        for (int o = 32; o > 0; o >>= 1) {
            s  += __shfl_xor(s, o);
            ss += __shfl_xor(ss, o);
        }
        float mean = s * (1.0f / DIMX);
        float var  = ss * (1.0f / DIMX) - mean * mean;
        float rstd = rsqrtf(var + 1e-5f);

        #pragma unroll
        for (int i = 0; i < 4; i++) {
            float4 g = ((const float4*)gamma)[lane + 64 * i];
            half4 o;
            o.x = (_Float16)((v[i].x - mean) * rstd * g.x);
            o.y = (_Float16)((v[i].y - mean) * rstd * g.y);
            o.z = (_Float16)((v[i].z - mean) * rstd * g.z);
            o.w = (_Float16)((v[i].w - mean) * rstd * g.w);
            *(half4*)(xo + (lane + 64 * i) * 4) = o;
        }
    } else {
        int idx = blockIdx.x - ROWS / 4;   // 0..4095
        int bx = idx & 127, by = idx >> 7; // 128 x 32
        const float* W; _Float16* WT; int N, n0;
        if (bx < 96) { W = Wq; WT = WqT; N = QKVW; n0 = bx * 32; }
        else         { W = Wo; WT = WoT; N = DIMX; n0 = (bx - 96) * 32; }
        int k0 = by * 32;
        int tx = t & 31, ty = t >> 5;      // 32 x 8
        #pragma unroll
        for (int i = 0; i < 32; i += 8)
            tile[ty + i][tx] = W[(size_t)(k0 + ty + i) * N + n0 + tx];
        __syncthreads();
        #pragma unroll
        for (int i = 0; i < 32; i += 8)
            WT[(size_t)(n0 + ty + i) * 1024 + k0 + tx] = (_Float16)tile[tx][ty + i];
    }
}

// ---------------------------------------------------------------------------
// Kernel 2: fused QKV GEMM + RMS(q,k) + per-head repack + V-transpose-store.
// DOUBLE-BUFFERED K/V staging: one barrier per iter, prefetch issued right
// after the barrier -> full compute phase of DMA latency hiding.
// Operand-swapped MFMA: wave subtile = one head x 64 tokens, full dh in-wave.
// ---------------------------------------------------------------------------
__global__ __launch_bounds__(256) void hgemm_qkv(const _Float16* __restrict__ A,
                                                 const _Float16* __restrict__ BT,
                                                 const float* __restrict__ qg,
                                                 const float* __restrict__ kg,
                                                 _Float16* __restrict__ qf,
                                                 _Float16* __restrict__ kf,
                                                 _Float16* __restrict__ vt) {
    __shared__ _Float16 As[2][128 * 64];
    __shared__ _Float16 Bs[2][128 * 64];
    const int K = DIMX;

    int t = threadIdx.x;
    int wave = t >> 6, lane = t & 63;
    int quad = lane >> 4, l16 = lane & 15;
    int wm = (wave >> 1) * 64;           // token offset within tile
    int wn = (wave & 1) * 64;            // feature offset within tile
    size_t m0 = (size_t)blockIdx.y * 128, n0 = (size_t)blockIdx.x * 128;

    floatx4 acc[4][4] = {};   // C^T frags: row=feature(nf,quad,r), col=token(mf,l16)

    int sr = t >> 3, sg = t & 7;
    int swz = sg ^ (sr & 7);
    const _Float16* ag = A  + (m0 + sr) * (size_t)K + swz * 8;
    const _Float16* bg = BT + (n0 + sr) * (size_t)K + swz * 8;

    // prologue: tile 0 -> buffer 0
    #pragma unroll
    for (int i = 0; i < 4; i++) {
        GLD_LDS16(ag + (size_t)(i * 32) * K, (char*)As[0] + wave * 1024 + i * 4096);
        GLD_LDS16(bg + (size_t)(i * 32) * K, (char*)Bs[0] + wave * 1024 + i * 4096);
    }

    for (int kt = 0; kt < 16; kt++) {
        int cur = kt & 1;
        __syncthreads();   // drains buf[cur] DMA (in flight for a full compute phase)

        if (kt < 15) {
            int k0 = (kt + 1) * 64;
            #pragma unroll
            for (int i = 0; i < 4; i++) {
                GLD_LDS16(ag + (size_t)(i * 32) * K + k0,
                          (char*)As[cur ^ 1] + wave * 1024 + i * 4096);
                GLD_LDS16(bg + (size_t)(i * 32) * K + k0,
                          (char*)Bs[cur ^ 1] + wave * 1024 + i * 4096);
            }
        }

        half8 af[2][4], bf[2][4];
        #pragma unroll
        for (int kk = 0; kk < 2; kk++) {
            #pragma unroll
            for (int mf = 0; mf < 4; mf++)
                af[kk][mf] = *(const half8*)&As[cur][(wm + mf * 16 + l16) * 64
                                 + (((kk * 4 + quad) ^ (l16 & 7)) * 8)];
            #pragma unroll
            for (int nf = 0; nf < 4; nf++)
                bf[kk][nf] = *(const half8*)&Bs[cur][(wn + nf * 16 + l16) * 64
                                 + (((kk * 4 + quad) ^ (l16 & 7)) * 8)];
        }

        #pragma unroll
        for (int kk = 0; kk < 2; kk++)
            #pragma unroll
            for (int mf = 0; mf < 4; mf++)
                #pragma unroll
                for (int nf = 0; nf < 4; nf++)
                    acc[mf][nf] = __builtin_amdgcn_mfma_f32_16x16x32_f16(
                        bf[kk][nf], af[kk][mf], acc[mf][nf], 0, 0, 0);
    }

    // epilogue: which = 0:q 1:k 2:v (block-uniform)
    int which = (int)(n0 >> 10);
    int nloc  = ((int)n0 & 1023) + wn;   // feature offset within q/k/v
    int h = nloc >> 6;

    if (which < 2) {
        const float* g = (which == 0) ? qg : kg;
        float emul = (which == 0) ? LOG2E : 1.0f;
        _Float16* dstbuf = (which == 0) ? qf : kf;
        #pragma unroll
        for (int mf = 0; mf < 4; mf++) {
            size_t tok = m0 + wm + mf * 16 + l16;
            int b = (int)(tok >> 10), ntk = (int)(tok & 1023);
            _Float16* dst = dstbuf + (((size_t)(b * 16 + h)) * 1024 + ntk) * 64;
            float ss = 0.f;
            #pragma unroll
            for (int nf = 0; nf < 4; nf++)
                #pragma unroll
                for (int r = 0; r < 4; r++) ss += acc[mf][nf][r] * acc[mf][nf][r];
            ss += __shfl_xor(ss, 16);
            ss += __shfl_xor(ss, 32);
            float scale = 8.0f * emul / fmaxf(sqrtf(ss), 1e-12f);
            #pragma unroll
            for (int nf = 0; nf < 4; nf++) {
                half4 p;
                #pragma unroll
                for (int r = 0; r < 4; r++)
                    p[r] = (_Float16)(acc[mf][nf][r] * scale *
                                      g[h * 64 + nf * 16 + quad * 4 + r]);
                *(half4*)(dst + nf * 16 + quad * 4) = p;
            }
        }
    } else {
        // V: wave-private LDS transpose -> coalesced half8 stores.
        __syncthreads();   // all waves done reading As/Bs
        _Float16* myT = ((wave < 2) ? (_Float16*)As : (_Float16*)Bs)
                        + (wave & 1) * (64 * 68);
        #pragma unroll
        for (int mf = 0; mf < 4; mf++)
            #pragma unroll
            for (int nf = 0; nf < 4; nf++)
                #pragma unroll
                for (int r = 0; r < 4; r++)
                    myT[(nf * 16 + quad * 4 + r) * 68 + mf * 16 + l16] =
                        (_Float16)acc[mf][nf][r];
        // wave-private region: in-wave ds ordering handled by compiler waitcnt
        size_t tok0 = m0 + wm;
        int b = (int)(tok0 >> 10), ntk0 = (int)(tok0 & 1023);
        int nt = ntk0 >> 6;
        _Float16* vbase = vt + ((size_t)((b * 16 + h) * 16 + nt) * 64) * 64;
        int rr = lane >> 3, gg = lane & 7;
        #pragma unroll
        for (int j = 0; j < 8; j++) {
            int d2 = j * 8 + rr;
            half8 v8 = *(const half8*)&myT[d2 * 68 + gg * 8];
            *(half8*)(vbase + d2 * 64 + gg * 8) = v8;
        }
    }
}

// ---------------------------------------------------------------------------
// Kernel 3: flash attention, transposed dataflow, exp2 softmax, double-
// buffered K/V staging, bh-major block mapping for XCD-local K/V L2 reuse.
// ---------------------------------------------------------------------------
__global__ __launch_bounds__(256, 3) void flash_kernel(const _Float16* __restrict__ qf,
                                                       const _Float16* __restrict__ kf,
                                                       const _Float16* __restrict__ vt,
                                                       _Float16* __restrict__ obuf) {
    __shared__ _Float16 Ks[2][64 * 64];    // [buf][kcol][dh], group-swizzled
    __shared__ _Float16 VTs[2][64 * 64];   // [buf][dh][kcol], group-swizzled
    __shared__ _Float16 Ps[4][16][68];     // per-wave P^T [qrow][kcol], Sb=34

    int t = threadIdx.x;
    int wave = t >> 6, lane = t & 63;
    int quad = lane >> 4, l16 = lane & 15;
    int bh = blockIdx.x & 127, qt = blockIdx.x >> 7;

    const _Float16* qb = qf + ((size_t)bh * 1024 + qt * 128) * 64;
    const _Float16* kb = kf + (size_t)bh * 65536;
    const _Float16* vb = vt + (size_t)bh * 65536;

    half8 aq[2][2];
    #pragma unroll
    for (int st = 0; st < 2; st++) {
        const _Float16* qrow = qb + (wave * 32 + st * 16 + l16) * 64;
        aq[st][0] = *(const half8*)(qrow + quad * 8);
        aq[st][1] = *(const half8*)(qrow + 32 + quad * 8);
    }

    floatx4 o[2][4] = {};
    float m_i[2] = {-INFINITY, -INFINITY};
    float l_i[2] = {0.f, 0.f};

    int sr = t >> 3;
    int sg = t & 7;
    int swz = sg ^ (sr & 7);

    // prologue: tile 0 -> buffer 0
    #pragma unroll
    for (int i = 0; i < 2; i++) {
        GLD_LDS16(kb + (i * 32 + sr) * 64 + swz * 8, (char*)Ks[0]  + wave * 1024 + i * 4096);
        GLD_LDS16(vb + (i * 32 + sr) * 64 + swz * 8, (char*)VTs[0] + wave * 1024 + i * 4096);
    }

    for (int kt = 0; kt < 16; kt++) {
        int cur = kt & 1;
        __syncthreads();

        if (kt < 15) {
            const _Float16* kn = kb + (size_t)(kt + 1) * 4096;
            const _Float16* vn = vb + (size_t)(kt + 1) * 4096;
            #pragma unroll
            for (int i = 0; i < 2; i++) {
                GLD_LDS16(kn + (i * 32 + sr) * 64 + swz * 8,
                          (char*)Ks[cur ^ 1]  + wave * 1024 + i * 4096);
                GLD_LDS16(vn + (i * 32 + sr) * 64 + swz * 8,
                          (char*)VTs[cur ^ 1] + wave * 1024 + i * 4096);
            }
        }

        #pragma unroll
        for (int st = 0; st < 2; st++) {
            // S^T = K Q^T (log2-domain scores; qf pre-scaled by LOG2E)
            floatx4 sc[4] = {};
            #pragma unroll
            for (int kc = 0; kc < 2; kc++) {
                #pragma unroll
                for (int nf = 0; nf < 4; nf++) {
                    half8 ak = *(const half8*)&Ks[cur][(nf * 16 + l16) * 64
                                    + (((kc * 4 + quad) ^ (l16 & 7)) * 8)];
                    sc[nf] = __builtin_amdgcn_mfma_f32_16x16x32_f16(
                        ak, aq[st][kc], sc[nf], 0, 0, 0);
                }
            }

            // online softmax (base-2): lane owns one q-row
            float mx = sc[0][0];
            #pragma unroll
            for (int nf = 0; nf < 4; nf++)
                #pragma unroll
                for (int r = 0; r < 4; r++) mx = fmaxf(mx, sc[nf][r]);
            mx = fmaxf(mx, __shfl_xor(mx, 16));
            mx = fmaxf(mx, __shfl_xor(mx, 32));
            if (mx > m_i[st]) {
                float alpha = fexp2(m_i[st] - mx);
                l_i[st] *= alpha;
                #pragma unroll
                for (int nf = 0; nf < 4; nf++) o[st][nf] *= alpha;
                m_i[st] = mx;
            }
            float mcur = m_i[st];
            float psum = 0.f;
            #pragma unroll
            for (int nf = 0; nf < 4; nf++)
                #pragma unroll
                for (int r = 0; r < 4; r++) {
                    float p = fexp2(sc[nf][r] - mcur);
                    sc[nf][r] = p;
                    psum += p;
                }
            l_i[st] += psum;

            // P^T -> LDS (b64 writes; stride 68 elems = conflict-free)
            #pragma unroll
            for (int nf = 0; nf < 4; nf++) {
                half4 p4;
                #pragma unroll
                for (int r = 0; r < 4; r++) p4[r] = (_Float16)sc[nf][r];
                *(half4*)&Ps[wave][l16][nf * 16 + quad * 4] = p4;
            }

            // O^T += V^T P^T
            #pragma unroll
            for (int kc = 0; kc < 2; kc++) {
                half4 p0 = *(const half4*)&Ps[wave][l16][kc * 32 + quad * 8];
                half4 p1 = *(const half4*)&Ps[wave][l16][kc * 32 + quad * 8 + 4];
                half8 bp;
                #pragma unroll
                for (int j = 0; j < 4; j++) { bp[j] = p0[j]; bp[4 + j] = p1[j]; }
                #pragma unroll
                for (int nf = 0; nf < 4; nf++) {
                    half8 av = *(const half8*)&VTs[cur][(nf * 16 + l16) * 64
                                    + (((kc * 4 + quad) ^ (l16 & 7)) * 8)];
                    o[st][nf] = __builtin_amdgcn_mfma_f32_16x16x32_f16(
                        av, bp, o[st][nf], 0, 0, 0);
                }
            }
        }
    }

    int b = bh >> 4, h = bh & 15;
    #pragma unroll
    for (int st = 0; st < 2; st++) {
        float lsum = l_i[st];
        lsum += __shfl_xor(lsum, 16);
        lsum += __shfl_xor(lsum, 32);
        float inv = 1.0f / lsum;
        size_t row = (size_t)b * NSEQ + qt * 128 + wave * 32 + st * 16 + l16;
        #pragma unroll
        for (int nf = 0; nf < 4; nf++) {
            half4 o4;
            #pragma unroll
            for (int r = 0; r < 4; r++) o4[r] = (_Float16)(o[st][nf][r] * inv);
            *(half4*)(obuf + row * 1024 + h * 64 + nf * 16 + quad * 4) = o4;
        }
    }
}

// ---------------------------------------------------------------------------
// Kernel 4: out-projection GEMM, double-buffered, fp32 out, float4 stores.
// ---------------------------------------------------------------------------
__global__ __launch_bounds__(256) void hgemm_out(const _Float16* __restrict__ A,
                                                 const _Float16* __restrict__ BT,
                                                 float* __restrict__ C) {
    __shared__ _Float16 As[2][128 * 64];
    __shared__ _Float16 Bs[2][128 * 64];
    const int K = DIMX, N = DIMX;

    int t = threadIdx.x;
    int wave = t >> 6, lane = t & 63;
    int quad = lane >> 4, l16 = lane & 15;
    int wm = (wave >> 1) * 64, wn = (wave & 1) * 64;
    size_t m0 = (size_t)blockIdx.y * 128, n0 = (size_t)blockIdx.x * 128;

    floatx4 acc[4][4] = {};

    int sr = t >> 3, sg = t & 7;
    int swz = sg ^ (sr & 7);
    const _Float16* ag = A  + (m0 + sr) * (size_t)K + swz * 8;
    const _Float16* bg = BT + (n0 + sr) * (size_t)K + swz * 8;

    #pragma unroll
    for (int i = 0; i < 4; i++) {
        GLD_LDS16(ag + (size_t)(i * 32) * K, (char*)As[0] + wave * 1024 + i * 4096);
        GLD_LDS16(bg + (size_t)(i * 32) * K, (char*)Bs[0] + wave * 1024 + i * 4096);
    }

    for (int kt = 0; kt < 16; kt++) {
        int cur = kt & 1;
        __syncthreads();

        if (kt < 15) {
            int k0 = (kt + 1) * 64;
            #pragma unroll
            for (int i = 0; i < 4; i++) {
                GLD_LDS16(ag + (size_t)(i * 32) * K + k0,
                          (char*)As[cur ^ 1] + wave * 1024 + i * 4096);
                GLD_LDS16(bg + (size_t)(i * 32) * K + k0,
                          (char*)Bs[cur ^ 1] + wave * 1024 + i * 4096);
            }
        }

        half8 af[2][4], bf[2][4];
        #pragma unroll
        for (int kk = 0; kk < 2; kk++) {
            #pragma unroll
            for (int mf = 0; mf < 4; mf++)
                af[kk][mf] = *(const half8*)&As[cur][(wm + mf * 16 + l16) * 64
                                 + (((kk * 4 + quad) ^ (l16 & 7)) * 8)];
            #pragma unroll
            for (int nf = 0; nf < 4; nf++)
                bf[kk][nf] = *(const half8*)&Bs[cur][(wn + nf * 16 + l16) * 64
                                 + (((kk * 4 + quad) ^ (l16 & 7)) * 8)];
        }

        #pragma unroll
        for (int kk = 0; kk < 2; kk++)
            #pragma unroll
            for (int mf = 0; mf < 4; mf++)
                #pragma unroll
                for (int nf = 0; nf < 4; nf++)
                    acc[mf][nf] = __builtin_amdgcn_mfma_f32_16x16x32_f16(
                        bf[kk][nf], af[kk][mf], acc[mf][nf], 0, 0, 0);
    }

    #pragma unroll
    for (int mf = 0; mf < 4; mf++) {
        size_t tok = m0 + wm + mf * 16 + l16;
        #pragma unroll
        for (int nf = 0; nf < 4; nf++)
            *(floatx4*)(C + tok * N + n0 + wn + nf * 16 + quad * 4) = acc[mf][nf];
    }
}

// ---------------------------------------------------------------------------
extern "C" void kernel_launch(void* const* d_in, const int* in_sizes, int n_in,
                              void* d_out, int out_size, void* d_ws, size_t ws_size,
                              hipStream_t stream) {
    const float* x     = (const float*)d_in[0];
    const float* ln_g  = (const float*)d_in[1];
    const float* q_g   = (const float*)d_in[2];
    const float* k_g   = (const float*)d_in[3];
    const float* w_qkv = (const float*)d_in[4];
    const float* w_out = (const float*)d_in[5];
    float* out = (float*)d_out;

    // workspace (88 MB):
    //   [0,16)  xn   [16,22) wqkvT  [22,24) woutT
    //   [24,40) qf   [40,56) kf     [56,72) vt    [72,88) obuf
    char* base = (char*)d_ws;
    _Float16* xn    = (_Float16*)(base);
    _Float16* wqkvT = (_Float16*)(base + (16ull << 20));
    _Float16* woutT = (_Float16*)(base + (22ull << 20));
    _Float16* qf    = (_Float16*)(base + (24ull << 20));
    _Float16* kf    = (_Float16*)(base + (40ull << 20));
    _Float16* vt    = (_Float16*)(base + (56ull << 20));
    _Float16* obuf  = (_Float16*)(base + (72ull << 20));

    lnw_kernel<<<ROWS / 4 + 4096, 256, 0, stream>>>(x, ln_g, w_qkv, w_out,
                                                    xn, wqkvT, woutT);

    dim3 g1(QKVW / 128, ROWS / 128);
    hgemm_qkv<<<g1, 256, 0, stream>>>(xn, wqkvT, q_g, k_g, qf, kf, vt);

    flash_kernel<<<NB * HEADS * (NSEQ / 128), 256, 0, stream>>>(qf, kf, vt, obuf);

    dim3 g2(DIMX / 128, ROWS / 128);
    hgemm_out<<<g2, 256, 0, stream>>>(obuf, woutT, out);
}